// Round 12
// baseline (276.913 us; speedup 1.0000x reference)
//
#include <hip/hip_runtime.h>
#include <stdint.h>

// ---------------------------------------------------------------------------
// cha_third_conv: polynomial channel expansion (L=8, orders 1..3) + 1x1 conv.
// GEMM view: M=B*H*W=12544, N=256, K=32 groups * 164 feats (padded to 192).
// Round 12 (= round 11 resubmitted; prior round was a broker outage, kernel
// never ran): r9 (PASSED, steady 126us) VERBATIM + split-K x2 ONLY.
//   r10 bundled three changes and failed; cvt_pk pk2 and closed-form kmap are
//   rolled back (bit-twiddled RTNE + search prep_w restored). Single delta:
//   blockIdx.z in {0,1} handles groups [z*16, z*16+16); grid 98x4x2 = 784
//   blocks (~3/CU, no tail); epilogue = device atomicAdd onto memset-zeroed
//   output; bias contributed by z==0 only. K-sum reassociation ~2^-24.
//   PASS -> r10 failure pinned on cvt_pk/kmap (stay banned).
//   FAIL -> atomics/memset indicted; revert to pure r9.
// ---------------------------------------------------------------------------

typedef short bf16x8 __attribute__((ext_vector_type(8)));
typedef float f32x4  __attribute__((ext_vector_type(4)));

__device__ __forceinline__ unsigned f2bf(float f) {
  unsigned u = __float_as_uint(f);
  return ((u + 0x7FFFu + ((u >> 16) & 1u)) >> 16) & 0xFFFFu;   // RTNE
}
__device__ __forceinline__ unsigned pk2(float lo, float hi) {
  return f2bf(lo) | (f2bf(hi) << 16);                          // r9 proven
}

#define ROW_S 200   // A-tile row stride in shorts (400 B) — r9 layout

// ---------------------------------------------------------------------------
// CANONICAL enumeration (r9 proven): pairs (a<=b) lex, triples (a<=b<=c) lex.
// ---------------------------------------------------------------------------
constexpr int PI(int b, int c) { return 8 * b - b * (b - 1) / 2 + (c - b); }

struct CTab {
  unsigned char pa[36], pb[36];             // pair slot q -> (a,b), a<=b
  unsigned char ta[120], tb[120], tc3[120]; // triple slot r -> (a,b,c) sorted
};
constexpr CTab gen_ctab() {
  CTab t{};
  int n = 0;
  for (int a = 0; a < 8; ++a)
    for (int b = a; b < 8; ++b) { t.pa[n] = (unsigned char)a; t.pb[n] = (unsigned char)b; ++n; }
  int m = 0;
  for (int a = 0; a < 8; ++a)
    for (int b = a; b < 8; ++b)
      for (int c = b; c < 8; ++c) {
        t.ta[m] = (unsigned char)a; t.tb[m] = (unsigned char)b; t.tc3[m] = (unsigned char)c; ++m;
      }
  return t;
}
constexpr CTab CT = gen_ctab();
__device__ const CTab dCT = CT;   // memory copy for prep_w

// feature K (canonical slot) from register x[8] and pair products pr[36]
template <int K>
__device__ __forceinline__ float featc(const float* __restrict__ x,
                                       const float* __restrict__ pr) {
  if constexpr (K < 8) {
    return x[K];
  } else if constexpr (K < 44) {
    return pr[K - 8];
  } else if constexpr (K < 164) {
    constexpr int r = K - 44;
    constexpr int a = CT.ta[r], b = CT.tb[r], c = CT.tc3[r];
    return x[a] * pr[PI(b, c)];            // pair product rounds first (as ref)
  } else {
    return 0.0f;                           // pad slots 164..167
  }
}

// one 16B chunk = canonical slots 8*CH .. 8*CH+7 at linear chunk position CH
template <int CH>
__device__ __forceinline__ void emit_chunk(const float* __restrict__ x,
                                           const float* __restrict__ pr,
                                           short* __restrict__ arow) {
  unsigned u0 = pk2(featc<CH * 8 + 0>(x, pr), featc<CH * 8 + 1>(x, pr));
  unsigned u1 = pk2(featc<CH * 8 + 2>(x, pr), featc<CH * 8 + 3>(x, pr));
  unsigned u2 = pk2(featc<CH * 8 + 4>(x, pr), featc<CH * 8 + 5>(x, pr));
  unsigned u3 = pk2(featc<CH * 8 + 6>(x, pr), featc<CH * 8 + 7>(x, pr));
  uint4 v; v.x = u0; v.y = u1; v.z = u2; v.w = u3;
  *reinterpret_cast<uint4*>(arow + (CH << 3)) = v;   // 16B aligned
}

// part0: chunks 0..10 (slots 0..87), part1: chunks 11..20 (88..167) — r9 split
__device__ __forceinline__ void stage_part0(const float* x, const float* pr, short* arow) {
  emit_chunk<0>(x, pr, arow);  emit_chunk<1>(x, pr, arow);  emit_chunk<2>(x, pr, arow);
  emit_chunk<3>(x, pr, arow);  emit_chunk<4>(x, pr, arow);  emit_chunk<5>(x, pr, arow);
  emit_chunk<6>(x, pr, arow);  emit_chunk<7>(x, pr, arow);  emit_chunk<8>(x, pr, arow);
  emit_chunk<9>(x, pr, arow);  emit_chunk<10>(x, pr, arow);
}
__device__ __forceinline__ void stage_part1(const float* x, const float* pr, short* arow) {
  emit_chunk<11>(x, pr, arow); emit_chunk<12>(x, pr, arow); emit_chunk<13>(x, pr, arow);
  emit_chunk<14>(x, pr, arow); emit_chunk<15>(x, pr, arow); emit_chunk<16>(x, pr, arow);
  emit_chunk<17>(x, pr, arow); emit_chunk<18>(x, pr, arow); emit_chunk<19>(x, pr, arow);
  emit_chunk<20>(x, pr, arow);
}

// ---------------------------------------------------------------------------
// prep_w — r9 VERBATIM (proven): weight -> bf16, padded, B-swizzled, permuted
// reference->canonical via monomial signature SEARCH against runtime pm2/pcm.
// ---------------------------------------------------------------------------
__global__ void prep_w(const float* __restrict__ w, const int* __restrict__ pm2,
                       const int* __restrict__ pcm, short* __restrict__ wout) {
  __shared__ unsigned short rsig[164];
  __shared__ short kmap[192];
  const int tid = threadIdx.x;

  if (tid < 164) {       // reference-order signatures from RUNTIME tables
    unsigned s;
    if (tid < 8) {
      s = 1u << (2 * tid);
    } else if (tid < 44) {
      int q = tid - 8;
      s = (1u << (2 * pm2[2 * q])) + (1u << (2 * pm2[2 * q + 1]));
    } else {
      int r = tid - 44;
      int c0 = pcm[2 * r], pos = pcm[2 * r + 1];
      s = (1u << (2 * c0)) + (1u << (2 * pm2[2 * pos])) + (1u << (2 * pm2[2 * pos + 1]));
    }
    rsig[tid] = (unsigned short)s;
  }
  __syncthreads();

  if (tid < 192) {       // canonical slot -> reference position
    int kk = -1;
    if (tid < 164) {
      unsigned cs;
      if (tid < 8) {
        cs = 1u << (2 * tid);
      } else if (tid < 44) {
        int q = tid - 8;
        cs = (1u << (2 * dCT.pa[q])) + (1u << (2 * dCT.pb[q]));
      } else {
        int r = tid - 44;
        cs = (1u << (2 * dCT.ta[r])) + (1u << (2 * dCT.tb[r])) + (1u << (2 * dCT.tc3[r]));
      }
      for (int t = 0; t < 164; ++t)
        if (rsig[t] == (unsigned short)cs) { kk = t; break; }
    }
    kmap[tid] = (short)kk;
  }
  __syncthreads();

  int e = blockIdx.x * 256 + tid;           // < 1,572,864
  int j  = e & 7;
  int n  = (e >> 3) & 255;
  int t2 = e >> 11;
  int q  = t2 & 3;
  int sg = t2 >> 2;                         // 0..191
  int g  = sg / 6;
  int s  = sg - g * 6;
  int kc = s * 32 + q * 8 + j;              // canonical slot 0..191
  int kk = kmap[kc];
  float val = (kk >= 0) ? w[n * 5248 + g * 164 + kk] : 0.0f;
  wout[e] = (short)f2bf(val);
}

// ---------------------------------------------------------------------------
// Main fused kernel — r9 skeleton + split-K z. Grid: (98 M-tiles of 128) x
// (4 N-tiles of 64) x (2 K-halves of 16 groups). Block: 256 thr = 4 waves.
// Epilogue: device-scope f32 atomicAdd onto zeroed output; bias from z=0 only.
// ---------------------------------------------------------------------------
__global__ __launch_bounds__(256, 2) void poly_gemm(
    const float* __restrict__ in, const short* __restrict__ wbf,
    const float* __restrict__ bias, float* __restrict__ out) {
  __shared__ __align__(16) short ldsA[128 * ROW_S];   // 51,200 B

  const int tid   = threadIdx.x;
  const int m0    = blockIdx.x * 128;
  const int n0    = blockIdx.y * 64;
  const int khalf = blockIdx.z;           // 0..1: groups [khalf*16, +16)
  const int lane  = tid & 63;
  const int wave  = tid >> 6;
  const int wm    = wave >> 1;       // M half
  const int wn    = wave & 1;        // N half
  const int quad  = lane >> 4;
  const int l16   = lane & 15;

  // one-time init: zero A-tile shorts 164..199 of every row (r9 verbatim)
  for (int i = tid; i < 128 * 36; i += 256) {
    int rr = i / 36, ss = 164 + (i - rr * 36);
    ldsA[rr * ROW_S + ss] = 0;
  }

  f32x4 acc[4][2];
#pragma unroll
  for (int mf = 0; mf < 4; mf++)
#pragma unroll
    for (int nf = 0; nf < 2; nf++) acc[mf][nf] = (f32x4){0.f, 0.f, 0.f, 0.f};

  const int pix  = tid & 127;
  const int part = tid >> 7;
  const int mg   = m0 + pix;
  const unsigned bb = (unsigned)mg / 3136u;
  const unsigned pp = (unsigned)mg - bb * 3136u;
  const float* xbase = in + (size_t)bb * 802816u + pp
                          + (size_t)(khalf * 128) * 3136u;   // +16 groups for z=1

  // prologue: first group's x into registers (coalesced: lane i -> pixel i)
  float xr[8];
#pragma unroll
  for (int c = 0; c < 8; ++c) xr[c] = xbase[(size_t)c * 3136u];

  for (int gi = 0; gi < 16; ++gi) {
    const int g = khalf * 16 + gi;        // global group (weights K index)

    // issue next group's x loads early — latency hides under stage + MFMA
    float xn[8];
    if (gi < 15) {
      const float* xp = xbase + (size_t)((gi + 1) * 8) * 3136u;
#pragma unroll
      for (int c = 0; c < 8; ++c) xn[c] = xp[(size_t)c * 3136u];
    }

    // stage: canonical features from register x, packed b128 chunk writes
    {
      short* arow = &ldsA[pix * ROW_S];
      float pr[36];
#pragma unroll
      for (int a = 0; a < 8; ++a)
#pragma unroll
        for (int b = a; b < 8; ++b) pr[PI(a, b)] = xr[a] * xr[b];
      if (part == 0) stage_part0(xr, pr, arow);
      else           stage_part1(xr, pr, arow);
    }
    __syncthreads();   // (b) A-tile ready

    // MFMA phase — r9 verbatim
#pragma unroll
    for (int ks = 0; ks < 6; ++ks) {
      bf16x8 af[4];
#pragma unroll
      for (int mf = 0; mf < 4; mf++) {
        int row = wm * 64 + mf * 16 + l16;
        af[mf] = *(const bf16x8*)(ldsA + row * ROW_S + ks * 32 + quad * 8);
      }
      bf16x8 bfr[2];
      const int sg = g * 6 + ks;
#pragma unroll
      for (int nf = 0; nf < 2; nf++) {
        int n = n0 + wn * 32 + nf * 16 + l16;
        bfr[nf] = *(const bf16x8*)(wbf + (((size_t)(sg * 4 + quad) * 256 + n) << 3));
      }
#pragma unroll
      for (int mf = 0; mf < 4; mf++)
#pragma unroll
        for (int nf = 0; nf < 2; nf++)
          acc[mf][nf] = __builtin_amdgcn_mfma_f32_16x16x32_bf16(af[mf], bfr[nf], acc[mf][nf], 0, 0, 0);
    }
    __syncthreads();   // (a) MFMA reads done before next stage overwrites

    if (gi < 15) {
#pragma unroll
      for (int c = 0; c < 8; ++c) xr[c] = xn[c];
    }
  }

  // epilogue: atomic-accumulate partials; bias contributed by z=0 only
#pragma unroll
  for (int nf = 0; nf < 2; nf++) {
    const int col = n0 + wn * 32 + nf * 16 + l16;
    const float bv = (khalf == 0) ? bias[col] : 0.0f;
#pragma unroll
    for (int mf = 0; mf < 4; mf++) {
#pragma unroll
      for (int r = 0; r < 4; r++) {
        int mg2 = m0 + wm * 64 + mf * 16 + quad * 4 + r;
        unsigned b2 = (unsigned)mg2 / 3136u;
        unsigned p2 = (unsigned)mg2 - b2 * 3136u;
        atomicAdd(&out[(size_t)b2 * 802816u + (size_t)col * 3136u + p2],
                  acc[mf][nf][r] + bv);
      }
    }
  }
}

extern "C" void kernel_launch(void* const* d_in, const int* in_sizes, int n_in,
                              void* d_out, int out_size, void* d_ws, size_t ws_size,
                              hipStream_t stream) {
  (void)in_sizes; (void)n_in; (void)out_size; (void)ws_size;
  const float* inp  = (const float*)d_in[0];
  const float* w    = (const float*)d_in[1];
  const float* bias = (const float*)d_in[2];
  const int*   pm2  = (const int*)d_in[3];
  const int*   pcm  = (const int*)d_in[4];
  short* wbf = (short*)d_ws;            // 3,145,728 B used

  // output = 4*256*56*56 f32 = 12,845,056 B; zero for split-K accumulation
  hipMemsetAsync(d_out, 0, 12845056, stream);
  prep_w<<<6144, 256, 0, stream>>>(w, pm2, pcm, wbf);
  poly_gemm<<<dim3(98, 4, 2), 256, 0, stream>>>(inp, wbf, bias, (float*)d_out);
}

// Round 13
// 200.318 us; speedup vs baseline: 1.3824x; 1.3824x over previous
//
#include <hip/hip_runtime.h>
#include <stdint.h>

// ---------------------------------------------------------------------------
// cha_third_conv: polynomial channel expansion (L=8, orders 1..3) + 1x1 conv.
// GEMM view: M=B*H*W=12544, N=256, K=32 groups * 164 feats (padded to 192).
// Round 13: r12's split-K atomics REVERTED (8x WRITE_SIZE amplification,
// 126->172us). Two safe-class changes on the r9 base (arithmetic untouched):
//   1) Geometry M128xN128: 512 thr = 8 waves (2Mx4N, wave M64xN32, 48
//      MFMA/wave like r9), grid 98x2=196. Stage duplication 4x -> 2x
//      (4 threads/pixel, balanced chunk ranges). Same 2-barrier loop,
//      ROW_S=200 tile, plain stores (no memset).
//   2) kmap search hoisted to a ONE-block build_kmap kernel (r9's exact
//      search, run once into workspace); prep_w is now a pure gather —
//      removes ~50us of redundant per-block search from the scored dur.
// Output bit-identical to r9 (same expressions, same K-accum order).
// ---------------------------------------------------------------------------

typedef short bf16x8 __attribute__((ext_vector_type(8)));
typedef float f32x4  __attribute__((ext_vector_type(4)));

__device__ __forceinline__ unsigned f2bf(float f) {
  unsigned u = __float_as_uint(f);
  return ((u + 0x7FFFu + ((u >> 16) & 1u)) >> 16) & 0xFFFFu;   // RTNE
}
__device__ __forceinline__ unsigned pk2(float lo, float hi) {
  return f2bf(lo) | (f2bf(hi) << 16);                          // r9 proven
}

#define ROW_S 200   // A-tile row stride in shorts (400 B) — r9 layout

// ---------------------------------------------------------------------------
// CANONICAL enumeration (r9 proven): pairs (a<=b) lex, triples (a<=b<=c) lex.
// ---------------------------------------------------------------------------
constexpr int PI(int b, int c) { return 8 * b - b * (b - 1) / 2 + (c - b); }

struct CTab {
  unsigned char pa[36], pb[36];             // pair slot q -> (a,b), a<=b
  unsigned char ta[120], tb[120], tc3[120]; // triple slot r -> (a,b,c) sorted
};
constexpr CTab gen_ctab() {
  CTab t{};
  int n = 0;
  for (int a = 0; a < 8; ++a)
    for (int b = a; b < 8; ++b) { t.pa[n] = (unsigned char)a; t.pb[n] = (unsigned char)b; ++n; }
  int m = 0;
  for (int a = 0; a < 8; ++a)
    for (int b = a; b < 8; ++b)
      for (int c = b; c < 8; ++c) {
        t.ta[m] = (unsigned char)a; t.tb[m] = (unsigned char)b; t.tc3[m] = (unsigned char)c; ++m;
      }
  return t;
}
constexpr CTab CT = gen_ctab();
__device__ const CTab dCT = CT;   // memory copy for build_kmap

// feature K (canonical slot) from register x[8] and pair products pr[36]
template <int K>
__device__ __forceinline__ float featc(const float* __restrict__ x,
                                       const float* __restrict__ pr) {
  if constexpr (K < 8) {
    return x[K];
  } else if constexpr (K < 44) {
    return pr[K - 8];
  } else if constexpr (K < 164) {
    constexpr int r = K - 44;
    constexpr int a = CT.ta[r], b = CT.tb[r], c = CT.tc3[r];
    return x[a] * pr[PI(b, c)];            // pair product rounds first (as ref)
  } else {
    return 0.0f;                           // pad slots 164..167
  }
}

// one 16B chunk = canonical slots 8*CH .. 8*CH+7 at linear chunk position CH
template <int CH>
__device__ __forceinline__ void emit_chunk(const float* __restrict__ x,
                                           const float* __restrict__ pr,
                                           short* __restrict__ arow) {
  unsigned u0 = pk2(featc<CH * 8 + 0>(x, pr), featc<CH * 8 + 1>(x, pr));
  unsigned u1 = pk2(featc<CH * 8 + 2>(x, pr), featc<CH * 8 + 3>(x, pr));
  unsigned u2 = pk2(featc<CH * 8 + 4>(x, pr), featc<CH * 8 + 5>(x, pr));
  unsigned u3 = pk2(featc<CH * 8 + 6>(x, pr), featc<CH * 8 + 7>(x, pr));
  uint4 v; v.x = u0; v.y = u1; v.z = u2; v.w = u3;
  *reinterpret_cast<uint4*>(arow + (CH << 3)) = v;   // 16B aligned
}

// 4-way part split (part = tid>>7): chunk ranges 0-5 / 6-10 / 11-15 / 16-20
__device__ __forceinline__ void stage_q0(const float* x, const float* pr, short* arow) {
  emit_chunk<0>(x, pr, arow);  emit_chunk<1>(x, pr, arow);  emit_chunk<2>(x, pr, arow);
  emit_chunk<3>(x, pr, arow);  emit_chunk<4>(x, pr, arow);  emit_chunk<5>(x, pr, arow);
}
__device__ __forceinline__ void stage_q1(const float* x, const float* pr, short* arow) {
  emit_chunk<6>(x, pr, arow);  emit_chunk<7>(x, pr, arow);  emit_chunk<8>(x, pr, arow);
  emit_chunk<9>(x, pr, arow);  emit_chunk<10>(x, pr, arow);
}
__device__ __forceinline__ void stage_q2(const float* x, const float* pr, short* arow) {
  emit_chunk<11>(x, pr, arow); emit_chunk<12>(x, pr, arow); emit_chunk<13>(x, pr, arow);
  emit_chunk<14>(x, pr, arow); emit_chunk<15>(x, pr, arow);
}
__device__ __forceinline__ void stage_q3(const float* x, const float* pr, short* arow) {
  emit_chunk<16>(x, pr, arow); emit_chunk<17>(x, pr, arow); emit_chunk<18>(x, pr, arow);
  emit_chunk<19>(x, pr, arow); emit_chunk<20>(x, pr, arow);
}

// ---------------------------------------------------------------------------
// build_kmap — ONE block; r9's exact signature search, result to workspace.
// kmap[kc] = reference index whose monomial == canonical slot kc (-1 = pad).
// ---------------------------------------------------------------------------
__global__ void build_kmap(const int* __restrict__ pm2, const int* __restrict__ pcm,
                           int* __restrict__ kmapG) {
  __shared__ unsigned short rsig[164];
  const int tid = threadIdx.x;

  if (tid < 164) {       // reference-order signatures from RUNTIME tables
    unsigned s;
    if (tid < 8) {
      s = 1u << (2 * tid);
    } else if (tid < 44) {
      int q = tid - 8;
      s = (1u << (2 * pm2[2 * q])) + (1u << (2 * pm2[2 * q + 1]));
    } else {
      int r = tid - 44;
      int c0 = pcm[2 * r], pos = pcm[2 * r + 1];
      s = (1u << (2 * c0)) + (1u << (2 * pm2[2 * pos])) + (1u << (2 * pm2[2 * pos + 1]));
    }
    rsig[tid] = (unsigned short)s;
  }
  __syncthreads();

  if (tid < 192) {       // canonical slot -> reference position
    int kk = -1;
    if (tid < 164) {
      unsigned cs;
      if (tid < 8) {
        cs = 1u << (2 * tid);
      } else if (tid < 44) {
        int q = tid - 8;
        cs = (1u << (2 * dCT.pa[q])) + (1u << (2 * dCT.pb[q]));
      } else {
        int r = tid - 44;
        cs = (1u << (2 * dCT.ta[r])) + (1u << (2 * dCT.tb[r])) + (1u << (2 * dCT.tc3[r]));
      }
      for (int t = 0; t < 164; ++t)
        if (rsig[t] == (unsigned short)cs) { kk = t; break; }
    }
    kmapG[tid] = kk;
  }
}

// ---------------------------------------------------------------------------
// prep_w — pure gather (search removed): weight -> bf16, padded 164->192,
// B-swizzled, permuted via precomputed kmap.
// ---------------------------------------------------------------------------
__global__ void prep_w(const float* __restrict__ w, const int* __restrict__ kmapG,
                       short* __restrict__ wout) {
  __shared__ short kmap[192];
  const int tid = threadIdx.x;
  if (tid < 192) kmap[tid] = (short)kmapG[tid];
  __syncthreads();

  int e = blockIdx.x * 256 + tid;           // < 1,572,864
  int j  = e & 7;
  int n  = (e >> 3) & 255;
  int t2 = e >> 11;
  int q  = t2 & 3;
  int sg = t2 >> 2;                         // 0..191
  int g  = sg / 6;
  int s  = sg - g * 6;
  int kc = s * 32 + q * 8 + j;              // canonical slot 0..191
  int kk = kmap[kc];
  float val = (kk >= 0) ? w[n * 5248 + g * 164 + kk] : 0.0f;
  wout[e] = (short)f2bf(val);
}

// ---------------------------------------------------------------------------
// Main fused kernel. Grid: (98 M-tiles of 128) x (2 N-tiles of 128).
// Block: 512 threads = 8 waves in 2(M) x 4(N); wave tile M64 x N32 (48 MFMA
// per wave per group, same as r9). Stage: 4 threads/pixel, balanced chunks.
// Sync: 2 __syncthreads per group (r9 proven).
// ---------------------------------------------------------------------------
__global__ __launch_bounds__(512, 2) void poly_gemm(
    const float* __restrict__ in, const short* __restrict__ wbf,
    const float* __restrict__ bias, float* __restrict__ out) {
  __shared__ __align__(16) short ldsA[128 * ROW_S];   // 51,200 B

  const int tid  = threadIdx.x;
  const int m0   = blockIdx.x * 128;
  const int n0   = blockIdx.y * 128;
  const int lane = tid & 63;
  const int wave = tid >> 6;        // 0..7
  const int wm   = wave >> 2;       // 0..1: M half (64 rows)
  const int wn   = wave & 3;        // 0..3: N quarter (32 cols)
  const int quad = lane >> 4;
  const int l16  = lane & 15;

  // one-time init: zero A-tile shorts 164..199 of every row
  for (int i = tid; i < 128 * 36; i += 512) {
    int rr = i / 36, ss = 164 + (i - rr * 36);
    ldsA[rr * ROW_S + ss] = 0;
  }

  f32x4 acc[4][2];
#pragma unroll
  for (int mf = 0; mf < 4; mf++)
#pragma unroll
    for (int nf = 0; nf < 2; nf++) acc[mf][nf] = (f32x4){0.f, 0.f, 0.f, 0.f};

  const int pix  = tid & 127;
  const int part = tid >> 7;        // 0..3
  const int mg   = m0 + pix;
  const unsigned bb = (unsigned)mg / 3136u;
  const unsigned pp = (unsigned)mg - bb * 3136u;
  const float* xbase = in + (size_t)bb * 802816u + pp;

  // prologue: group-0 x into registers (coalesced: threads 0..127 -> pixels)
  float xr[8];
#pragma unroll
  for (int c = 0; c < 8; ++c) xr[c] = xbase[(size_t)c * 3136u];

  for (int g = 0; g < 32; ++g) {
    // issue next group's x loads early — latency hides under stage + MFMA
    float xn[8];
    if (g < 31) {
      const float* xp = xbase + (size_t)((g + 1) * 8) * 3136u;
#pragma unroll
      for (int c = 0; c < 8; ++c) xn[c] = xp[(size_t)c * 3136u];
    }

    // stage: canonical features from register x, packed b128 chunk writes
    {
      short* arow = &ldsA[pix * ROW_S];
      float pr[36];
#pragma unroll
      for (int a = 0; a < 8; ++a)
#pragma unroll
        for (int b = a; b < 8; ++b) pr[PI(a, b)] = xr[a] * xr[b];
      if      (part == 0) stage_q0(xr, pr, arow);
      else if (part == 1) stage_q1(xr, pr, arow);
      else if (part == 2) stage_q2(xr, pr, arow);
      else                stage_q3(xr, pr, arow);
    }
    __syncthreads();   // (b) A-tile ready

    // MFMA phase — r9 core, wave tile M64 x N32
#pragma unroll
    for (int ks = 0; ks < 6; ++ks) {
      bf16x8 af[4];
#pragma unroll
      for (int mf = 0; mf < 4; mf++) {
        int row = wm * 64 + mf * 16 + l16;
        af[mf] = *(const bf16x8*)(ldsA + row * ROW_S + ks * 32 + quad * 8);
      }
      bf16x8 bfr[2];
      const int sg = g * 6 + ks;
#pragma unroll
      for (int nf = 0; nf < 2; nf++) {
        int n = n0 + wn * 32 + nf * 16 + l16;
        bfr[nf] = *(const bf16x8*)(wbf + (((size_t)(sg * 4 + quad) * 256 + n) << 3));
      }
#pragma unroll
      for (int mf = 0; mf < 4; mf++)
#pragma unroll
        for (int nf = 0; nf < 2; nf++)
          acc[mf][nf] = __builtin_amdgcn_mfma_f32_16x16x32_bf16(af[mf], bfr[nf], acc[mf][nf], 0, 0, 0);
    }
    __syncthreads();   // (a) MFMA reads done before next stage overwrites

    if (g < 31) {
#pragma unroll
      for (int c = 0; c < 8; ++c) xr[c] = xn[c];
    }
  }

  // epilogue: plain stores (full overwrite). D col = l16 ch, row = quad*4+r
#pragma unroll
  for (int nf = 0; nf < 2; nf++) {
    const int col = n0 + wn * 32 + nf * 16 + l16;
    const float bv = bias[col];
#pragma unroll
    for (int mf = 0; mf < 4; mf++) {
#pragma unroll
      for (int r = 0; r < 4; r++) {
        int mg2 = m0 + wm * 64 + mf * 16 + quad * 4 + r;
        unsigned b2 = (unsigned)mg2 / 3136u;
        unsigned p2 = (unsigned)mg2 - b2 * 3136u;
        out[(size_t)b2 * 802816u + (size_t)col * 3136u + p2] = acc[mf][nf][r] + bv;
      }
    }
  }
}

extern "C" void kernel_launch(void* const* d_in, const int* in_sizes, int n_in,
                              void* d_out, int out_size, void* d_ws, size_t ws_size,
                              hipStream_t stream) {
  (void)in_sizes; (void)n_in; (void)out_size; (void)ws_size;
  const float* inp  = (const float*)d_in[0];
  const float* w    = (const float*)d_in[1];
  const float* bias = (const float*)d_in[2];
  const int*   pm2  = (const int*)d_in[3];
  const int*   pcm  = (const int*)d_in[4];
  int*   kmapG = (int*)d_ws;                      // 768 B (+pad to 1024)
  short* wbf   = (short*)((char*)d_ws + 1024);    // 3,145,728 B

  build_kmap<<<1, 256, 0, stream>>>(pm2, pcm, kmapG);
  prep_w<<<6144, 256, 0, stream>>>(w, kmapG, wbf);
  poly_gemm<<<dim3(98, 2), 512, 0, stream>>>(inp, wbf, bias, (float*)d_out);
}

// Round 14
// 149.897 us; speedup vs baseline: 1.8474x; 1.3364x over previous
//
#include <hip/hip_runtime.h>
#include <stdint.h>

// ---------------------------------------------------------------------------
// cha_third_conv: polynomial channel expansion (L=8, orders 1..3) + 1x1 conv.
// GEMM view: M=B*H*W=12544, N=256, K=32 groups * 164 feats (padded to 192).
// Round 14: critical-path restructure (r13 steady was latency-bound: all
// pipes <20%, 2-barrier lockstep + unprefetched B). Math bit-identical to r9.
//   1) dbuf ldsA + ONE __syncthreads per group: stage(g+1)->buf^1 overlaps
//      MFMA(g)->buf; single barrier satisfies both hazards.
//   2) T14 B-prefetch: all 12 B-fragments of group g loaded to registers at
//      iteration top; stage VALU covers their L2 latency.
//   3) M64xN128, 256 thr = 4 waves, wave tile M64xN32 (48 MFMA/group, r9
//      ratio kept); LDS 51.2KB -> launch_bounds(256,3), grid 392, no B-dup.
// build_kmap/prep_w: r13 verbatim (proven).
// ---------------------------------------------------------------------------

typedef short bf16x8 __attribute__((ext_vector_type(8)));
typedef float f32x4  __attribute__((ext_vector_type(4)));

__device__ __forceinline__ unsigned f2bf(float f) {
  unsigned u = __float_as_uint(f);
  return ((u + 0x7FFFu + ((u >> 16) & 1u)) >> 16) & 0xFFFFu;   // RTNE
}
__device__ __forceinline__ unsigned pk2(float lo, float hi) {
  return f2bf(lo) | (f2bf(hi) << 16);                          // r9 proven
}

#define ROW_S 200   // A-tile row stride in shorts (400 B) — r9 layout

// ---------------------------------------------------------------------------
// CANONICAL enumeration (r9 proven): pairs (a<=b) lex, triples (a<=b<=c) lex.
// ---------------------------------------------------------------------------
constexpr int PI(int b, int c) { return 8 * b - b * (b - 1) / 2 + (c - b); }

struct CTab {
  unsigned char pa[36], pb[36];             // pair slot q -> (a,b), a<=b
  unsigned char ta[120], tb[120], tc3[120]; // triple slot r -> (a,b,c) sorted
};
constexpr CTab gen_ctab() {
  CTab t{};
  int n = 0;
  for (int a = 0; a < 8; ++a)
    for (int b = a; b < 8; ++b) { t.pa[n] = (unsigned char)a; t.pb[n] = (unsigned char)b; ++n; }
  int m = 0;
  for (int a = 0; a < 8; ++a)
    for (int b = a; b < 8; ++b)
      for (int c = b; c < 8; ++c) {
        t.ta[m] = (unsigned char)a; t.tb[m] = (unsigned char)b; t.tc3[m] = (unsigned char)c; ++m;
      }
  return t;
}
constexpr CTab CT = gen_ctab();
__device__ const CTab dCT = CT;   // memory copy for build_kmap

// feature K (canonical slot) from register x[8] and pair products pr[36]
template <int K>
__device__ __forceinline__ float featc(const float* __restrict__ x,
                                       const float* __restrict__ pr) {
  if constexpr (K < 8) {
    return x[K];
  } else if constexpr (K < 44) {
    return pr[K - 8];
  } else if constexpr (K < 164) {
    constexpr int r = K - 44;
    constexpr int a = CT.ta[r], b = CT.tb[r], c = CT.tc3[r];
    return x[a] * pr[PI(b, c)];            // pair product rounds first (as ref)
  } else {
    return 0.0f;                           // pad slots 164..167
  }
}

// one 16B chunk = canonical slots 8*CH .. 8*CH+7 at linear chunk position CH
template <int CH>
__device__ __forceinline__ void emit_chunk(const float* __restrict__ x,
                                           const float* __restrict__ pr,
                                           short* __restrict__ arow) {
  unsigned u0 = pk2(featc<CH * 8 + 0>(x, pr), featc<CH * 8 + 1>(x, pr));
  unsigned u1 = pk2(featc<CH * 8 + 2>(x, pr), featc<CH * 8 + 3>(x, pr));
  unsigned u2 = pk2(featc<CH * 8 + 4>(x, pr), featc<CH * 8 + 5>(x, pr));
  unsigned u3 = pk2(featc<CH * 8 + 6>(x, pr), featc<CH * 8 + 7>(x, pr));
  uint4 v; v.x = u0; v.y = u1; v.z = u2; v.w = u3;
  *reinterpret_cast<uint4*>(arow + (CH << 3)) = v;   // 16B aligned
}

// 4-way part split (part = wave): chunk ranges 0-5 / 6-10 / 11-15 / 16-20
__device__ __forceinline__ void stage_q0(const float* x, const float* pr, short* arow) {
  emit_chunk<0>(x, pr, arow);  emit_chunk<1>(x, pr, arow);  emit_chunk<2>(x, pr, arow);
  emit_chunk<3>(x, pr, arow);  emit_chunk<4>(x, pr, arow);  emit_chunk<5>(x, pr, arow);
}
__device__ __forceinline__ void stage_q1(const float* x, const float* pr, short* arow) {
  emit_chunk<6>(x, pr, arow);  emit_chunk<7>(x, pr, arow);  emit_chunk<8>(x, pr, arow);
  emit_chunk<9>(x, pr, arow);  emit_chunk<10>(x, pr, arow);
}
__device__ __forceinline__ void stage_q2(const float* x, const float* pr, short* arow) {
  emit_chunk<11>(x, pr, arow); emit_chunk<12>(x, pr, arow); emit_chunk<13>(x, pr, arow);
  emit_chunk<14>(x, pr, arow); emit_chunk<15>(x, pr, arow);
}
__device__ __forceinline__ void stage_q3(const float* x, const float* pr, short* arow) {
  emit_chunk<16>(x, pr, arow); emit_chunk<17>(x, pr, arow); emit_chunk<18>(x, pr, arow);
  emit_chunk<19>(x, pr, arow); emit_chunk<20>(x, pr, arow);
}

__device__ __forceinline__ void stage_dispatch(int part, const float* x,
                                               short* arow) {
  float pr[36];
#pragma unroll
  for (int a = 0; a < 8; ++a)
#pragma unroll
    for (int b = a; b < 8; ++b) pr[PI(a, b)] = x[a] * x[b];
  if      (part == 0) stage_q0(x, pr, arow);
  else if (part == 1) stage_q1(x, pr, arow);
  else if (part == 2) stage_q2(x, pr, arow);
  else                stage_q3(x, pr, arow);
}

// ---------------------------------------------------------------------------
// build_kmap — ONE block; r9's exact signature search, result to workspace.
// ---------------------------------------------------------------------------
__global__ void build_kmap(const int* __restrict__ pm2, const int* __restrict__ pcm,
                           int* __restrict__ kmapG) {
  __shared__ unsigned short rsig[164];
  const int tid = threadIdx.x;

  if (tid < 164) {       // reference-order signatures from RUNTIME tables
    unsigned s;
    if (tid < 8) {
      s = 1u << (2 * tid);
    } else if (tid < 44) {
      int q = tid - 8;
      s = (1u << (2 * pm2[2 * q])) + (1u << (2 * pm2[2 * q + 1]));
    } else {
      int r = tid - 44;
      int c0 = pcm[2 * r], pos = pcm[2 * r + 1];
      s = (1u << (2 * c0)) + (1u << (2 * pm2[2 * pos])) + (1u << (2 * pm2[2 * pos + 1]));
    }
    rsig[tid] = (unsigned short)s;
  }
  __syncthreads();

  if (tid < 192) {       // canonical slot -> reference position
    int kk = -1;
    if (tid < 164) {
      unsigned cs;
      if (tid < 8) {
        cs = 1u << (2 * tid);
      } else if (tid < 44) {
        int q = tid - 8;
        cs = (1u << (2 * dCT.pa[q])) + (1u << (2 * dCT.pb[q]));
      } else {
        int r = tid - 44;
        cs = (1u << (2 * dCT.ta[r])) + (1u << (2 * dCT.tb[r])) + (1u << (2 * dCT.tc3[r]));
      }
      for (int t = 0; t < 164; ++t)
        if (rsig[t] == (unsigned short)cs) { kk = t; break; }
    }
    kmapG[tid] = kk;
  }
}

// ---------------------------------------------------------------------------
// prep_w — pure gather: weight -> bf16, padded 164->192, B-swizzled, permuted
// via precomputed kmap.  ws[((sg*4+q)*256+n)*8+j] layout as before.
// ---------------------------------------------------------------------------
__global__ void prep_w(const float* __restrict__ w, const int* __restrict__ kmapG,
                       short* __restrict__ wout) {
  __shared__ short kmap[192];
  const int tid = threadIdx.x;
  if (tid < 192) kmap[tid] = (short)kmapG[tid];
  __syncthreads();

  int e = blockIdx.x * 256 + tid;           // < 1,572,864
  int j  = e & 7;
  int n  = (e >> 3) & 255;
  int t2 = e >> 11;
  int q  = t2 & 3;
  int sg = t2 >> 2;                         // 0..191
  int g  = sg / 6;
  int s  = sg - g * 6;
  int kc = s * 32 + q * 8 + j;              // canonical slot 0..191
  int kk = kmap[kc];
  float val = (kk >= 0) ? w[n * 5248 + g * 164 + kk] : 0.0f;
  wout[e] = (short)f2bf(val);
}

// ---------------------------------------------------------------------------
// Main fused kernel. Grid: (196 M-tiles of 64) x (2 N-tiles of 128).
// Block: 256 threads = 4 waves; wave w = N-quarter wn (tile M64 x N32) AND
// stage part w. Double-buffered ldsA, ONE __syncthreads per group, B
// prefetched to registers at iteration top (stage VALU covers L2 latency).
// ---------------------------------------------------------------------------
__global__ __launch_bounds__(256, 3) void poly_gemm(
    const float* __restrict__ in, const short* __restrict__ wbf,
    const float* __restrict__ bias, float* __restrict__ out) {
  __shared__ __align__(16) short ldsA[2][64 * ROW_S];   // 51,200 B

  const int tid  = threadIdx.x;
  const int m0   = blockIdx.x * 64;
  const int n0   = blockIdx.y * 128;
  const int lane = tid & 63;        // pixel within tile
  const int wave = tid >> 6;        // 0..3: wn AND stage part
  const int quad = lane >> 4;
  const int l16  = lane & 15;

  // zero k-pad shorts 168..199 of both buffers (4 x uint4 per row)
  {
    uint4 z; z.x = 0u; z.y = 0u; z.z = 0u; z.w = 0u;
    for (int i = tid; i < 2 * 64 * 4; i += 256) {
      int b   = i >> 8;
      int rem = i & 255;
      int row = rem >> 2;
      int q4  = rem & 3;
      *reinterpret_cast<uint4*>(&ldsA[b][row * ROW_S + 168 + q4 * 8]) = z;
    }
  }

  f32x4 acc[4][2];
#pragma unroll
  for (int mf = 0; mf < 4; mf++)
#pragma unroll
    for (int nf = 0; nf < 2; nf++) acc[mf][nf] = (f32x4){0.f, 0.f, 0.f, 0.f};

  const unsigned bb = (unsigned)m0 / 3136u;     // tile fits one image (3136=49*64)
  const unsigned pp = (unsigned)m0 - bb * 3136u;
  const float* xbase = in + (size_t)bb * 802816u + pp + lane;

  // prologue: x(0) -> stage ldsA[0]; then x(1) -> xr; one barrier
  float xr[8];
#pragma unroll
  for (int c = 0; c < 8; ++c) xr[c] = xbase[(size_t)c * 3136u];
  stage_dispatch(wave, xr, &ldsA[0][lane * ROW_S]);
#pragma unroll
  for (int c = 0; c < 8; ++c) xr[c] = xbase[(size_t)(8 + c) * 3136u];
  __syncthreads();

  int cur = 0;
  for (int g = 0; g < 32; ++g) {
    // (1) issue: B fragments of group g into registers (consumed by MFMA below)
    bf16x8 ball[6][2];
#pragma unroll
    for (int ks = 0; ks < 6; ++ks) {
      const int sg = g * 6 + ks;
#pragma unroll
      for (int nf = 0; nf < 2; ++nf) {
        int n = n0 + wave * 32 + nf * 16 + l16;
        ball[ks][nf] = *(const bf16x8*)(wbf + (((size_t)(sg * 4 + quad) * 256 + n) << 3));
      }
    }
    // (1b) issue: x(g+2) loads
    float xn[8];
    if (g + 2 < 32) {
      const float* xp = xbase + (size_t)((g + 2) * 8) * 3136u;
#pragma unroll
      for (int c = 0; c < 8; ++c) xn[c] = xp[(size_t)c * 3136u];
    }

    // (2) stage(g+1) from xr into the other buffer — VALU covers B/x latency
    if (g + 1 < 32)
      stage_dispatch(wave, xr, &ldsA[cur ^ 1][lane * ROW_S]);

    // (3) MFMA(g) from ldsA[cur] and prefetched B
    const short* abuf = ldsA[cur];
#pragma unroll
    for (int ks = 0; ks < 6; ++ks) {
      bf16x8 af[4];
#pragma unroll
      for (int mf = 0; mf < 4; ++mf)
        af[mf] = *(const bf16x8*)(abuf + (mf * 16 + l16) * ROW_S + ks * 32 + quad * 8);
#pragma unroll
      for (int mf = 0; mf < 4; ++mf)
#pragma unroll
        for (int nf = 0; nf < 2; ++nf)
          acc[mf][nf] = __builtin_amdgcn_mfma_f32_16x16x32_bf16(af[mf], ball[ks][nf], acc[mf][nf], 0, 0, 0);
    }

    if (g + 2 < 32) {
#pragma unroll
      for (int c = 0; c < 8; ++c) xr[c] = xn[c];
    }
    cur ^= 1;
    __syncthreads();   // single barrier: buf[cur^1] staged AND buf[cur] reads done
  }

  // epilogue: plain stores. D col = l16 (out ch), row = quad*4 + r (pixel)
#pragma unroll
  for (int nf = 0; nf < 2; nf++) {
    const int col = n0 + wave * 32 + nf * 16 + l16;
    const float bv = bias[col];
#pragma unroll
    for (int mf = 0; mf < 4; mf++) {
#pragma unroll
      for (int r = 0; r < 4; r++) {
        unsigned p2 = pp + (unsigned)(mf * 16 + quad * 4 + r);
        out[(size_t)bb * 802816u + (size_t)col * 3136u + p2] = acc[mf][nf][r] + bv;
      }
    }
  }
}

extern "C" void kernel_launch(void* const* d_in, const int* in_sizes, int n_in,
                              void* d_out, int out_size, void* d_ws, size_t ws_size,
                              hipStream_t stream) {
  (void)in_sizes; (void)n_in; (void)out_size; (void)ws_size;
  const float* inp  = (const float*)d_in[0];
  const float* w    = (const float*)d_in[1];
  const float* bias = (const float*)d_in[2];
  const int*   pm2  = (const int*)d_in[3];
  const int*   pcm  = (const int*)d_in[4];
  int*   kmapG = (int*)d_ws;                      // 768 B (+pad to 1024)
  short* wbf   = (short*)((char*)d_ws + 1024);    // 3,145,728 B

  build_kmap<<<1, 256, 0, stream>>>(pm2, pcm, kmapG);
  prep_w<<<6144, 256, 0, stream>>>(w, kmapG, wbf);
  poly_gemm<<<dim3(196, 2), 256, 0, stream>>>(inp, wbf, bias, (float*)d_out);
}